// Round 6
// baseline (197.600 us; speedup 1.0000x reference)
//
#include <hip/hip_runtime.h>

#define N_NODES 100000
#define D_FEAT 128
#define N_CLASSES 32
#define B4SHIFT 6
#define NB4 1563          // ceil(100000/64) dst buckets of 64 nodes
#define EPB 16384         // edges per partition block (two-pass over global)
#define CAPB4 1280        // per-bucket capacity (mean 1023 + 8 sigma)

typedef __attribute__((ext_vector_type(8))) short short8;
typedef __attribute__((ext_vector_type(4))) float f32x4;

__device__ __forceinline__ unsigned short f2bf(float f) {
  unsigned u = __float_as_uint(f);
  u += 0x7fffu + ((u >> 16) & 1);   // round-to-nearest-even
  return (unsigned short)(u >> 16);
}

// pack two f32 -> two bf16 (RNE) in one instruction
__device__ __forceinline__ unsigned cvtpk(float lo, float hi) {
  unsigned r;
  asm("v_cvt_pk_bf16_f32 %0, %1, %2" : "=v"(r) : "v"(lo), "v"(hi));
  return r;
}

// ---------- prep: W -> bf16 + zero bucket counters ----------
__global__ __launch_bounds__(256) void gin_prep(const float* __restrict__ W,
                                                unsigned short* __restrict__ Wb,
                                                int* __restrict__ gcount) {
  int i = blockIdx.x * 256 + threadIdx.x;
  if (i < D_FEAT * N_CLASSES) Wb[i] = f2bf(W[i]);
  if (i < NB4) gcount[i] = 0;
}

// ---------- fused mid: blocks [0,GBr) partition edges, rest MFMA projection ----------
// Partition (64-node buckets): two passes over this block's global edge slice
// (histogram, then scatter; dst read twice to keep VGPRs low) -> reserve global
// per-bucket ranges with one atomicAdd per (block,bucket) -> direct scattered
// store. Runs of ~10.5 consecutive slots per (block,bucket) keep line-amp ~2x.
// LDS 12.5 KB (cnt reused as cur). Projection: wave = 16 nodes x 32 classes;
// writes f32 y (exact self-term) AND bf16 yh (gather aggregate table).
__global__ __launch_bounds__(256) void gin_mid(
    const float* __restrict__ x, const unsigned short* __restrict__ Wb,
    float* __restrict__ y, unsigned short* __restrict__ yh,
    const int* __restrict__ src, const int* __restrict__ dst,
    int* __restrict__ gcount, unsigned* __restrict__ bucketed,
    int E, int GBr) {
  __shared__ int cnt[NB4];     // 6.25 KB (histogram, then reused as cursor)
  __shared__ int gbase[NB4];   // 6.25 KB
  int tid = threadIdx.x;

  if ((int)blockIdx.x >= GBr) {
    // ================= projection path =================
    int pb = blockIdx.x - GBr;
    int wave = tid >> 6, lane = tid & 63;
    int node_base = pb * 64 + wave * 16;
    if (node_base >= N_NODES) return;
    int m = lane & 15, quad = lane >> 4;

    short8 bfrag[2][4];
#pragma unroll
    for (int cb = 0; cb < 2; ++cb) {
      const unsigned short* wr = Wb + (cb * 16 + m) * D_FEAT + quad * 8;
#pragma unroll
      for (int ks = 0; ks < 4; ++ks)
        bfrag[cb][ks] = *(const short8*)(wr + ks * 32);
    }

    const float* xr = x + (size_t)(node_base + m) * D_FEAT + quad * 8;
    short8 afrag[4];
#pragma unroll
    for (int ks = 0; ks < 4; ++ks) {
      float4 f0 = *(const float4*)(xr + ks * 32);
      float4 f1 = *(const float4*)(xr + ks * 32 + 4);
      union { uint4 u; short8 s; } au;
      au.u.x = cvtpk(f0.x, f0.y);
      au.u.y = cvtpk(f0.z, f0.w);
      au.u.z = cvtpk(f1.x, f1.y);
      au.u.w = cvtpk(f1.z, f1.w);
      afrag[ks] = au.s;
    }

    f32x4 acc0 = {0.f, 0.f, 0.f, 0.f};
    f32x4 acc1 = {0.f, 0.f, 0.f, 0.f};
#pragma unroll
    for (int ks = 0; ks < 4; ++ks) {
      acc0 = __builtin_amdgcn_mfma_f32_16x16x32_bf16(afrag[ks], bfrag[0][ks], acc0, 0, 0, 0);
      acc1 = __builtin_amdgcn_mfma_f32_16x16x32_bf16(afrag[ks], bfrag[1][ks], acc1, 0, 0, 0);
    }

#pragma unroll
    for (int r = 0; r < 4; ++r) {
      int node = node_base + quad * 4 + r;
      y[(size_t)node * N_CLASSES + m] = acc0[r];
      y[(size_t)node * N_CLASSES + 16 + m] = acc1[r];
      unsigned pk = cvtpk(acc0[r], acc1[r]);   // [bf16(col m) | bf16(col m+16)]
      yh[(size_t)node * N_CLASSES + m] = (unsigned short)(pk & 0xFFFFu);
      yh[(size_t)node * N_CLASSES + 16 + m] = (unsigned short)(pk >> 16);
    }
    return;
  }

  // ================= partition path (12.5 KB LDS) =================
  int blk = blockIdx.x;
  for (int i = tid; i < NB4; i += 256) cnt[i] = 0;
  __syncthreads();
  int base = blk * EPB;

  // pass 1: histogram over this block's slice
  for (int k = 0; k < EPB / 256; ++k) {
    int e = base + k * 256 + tid;
    if (e < E) atomicAdd(&cnt[dst[e] >> B4SHIFT], 1);
  }
  __syncthreads();

  // reserve global ranges (within-bucket order irrelevant -> no scan anywhere)
  for (int i = tid; i < NB4; i += 256) {
    int c = cnt[i];
    gbase[i] = c ? atomicAdd(&gcount[i], c) : 0;
  }
  __syncthreads();
  for (int i = tid; i < NB4; i += 256) cnt[i] = 0;   // reuse as cursor
  __syncthreads();

  // pass 2: direct scattered store (runs of ~10.5 consecutive slots per bucket)
  for (int k = 0; k < EPB / 256; ++k) {
    int e = base + k * 256 + tid;
    if (e < E) {
      int d = dst[e];
      int b4 = d >> B4SHIFT;
      int r = atomicAdd(&cnt[b4], 1);
      int ga = gbase[b4] + r;
      if (ga < CAPB4)
        bucketed[(size_t)b4 * CAPB4 + ga] =
            (unsigned)src[e] | ((unsigned)(d & 63) << 17);
    }
  }
}

// ---------- gather: one block per 64-node bucket ----------
// Stage own segment into LDS (read once), 64-way counting sort in LDS, then
// 8-threads-per-node register accumulation from the bf16 yh table (8 B random
// loads; the 8 q-threads of a node cover one 64 B row contiguously). Self-term
// from f32 y. out = agg + y + b.
__global__ __launch_bounds__(512) void gin_gather_s(
    const int* __restrict__ gcount, const unsigned* __restrict__ bucketed,
    const float* __restrict__ y, const unsigned short* __restrict__ yh,
    const float* __restrict__ bias, float* __restrict__ out) {
  __shared__ unsigned stage[CAPB4];   // 5 KB
  __shared__ unsigned sorted[CAPB4];  // 5 KB
  __shared__ int cnt[64];
  __shared__ int off[65];
  __shared__ int cur[64];
  int tid = threadIdx.x;
  int b4 = blockIdx.x;
  int len = gcount[b4];
  if (len > CAPB4) len = CAPB4;
  const unsigned* bb = bucketed + (size_t)b4 * CAPB4;
  if (tid < 64) cnt[tid] = 0;
  __syncthreads();
  // single global pass: stage + count (every entry belongs to this block)
  for (int i = tid; i < len; i += 512) {
    unsigned p = bb[i];
    stage[i] = p;
    atomicAdd(&cnt[(p >> 17) & 63], 1);
  }
  __syncthreads();
  if (tid == 0) off[0] = 0;
  if (tid < 64) off[tid + 1] = cnt[tid];
  __syncthreads();
  for (int o = 1; o < 64; o <<= 1) {
    int v = (tid < 64 && tid >= o) ? off[tid + 1 - o] : 0;
    __syncthreads();
    if (tid < 64) off[tid + 1] += v;
    __syncthreads();
  }
  if (tid < 64) cur[tid] = off[tid];
  __syncthreads();
  // LDS -> LDS counting-scatter (pos < len <= CAPB4 by construction)
  for (int i = tid; i < len; i += 512) {
    unsigned p = stage[i];
    int pos = atomicAdd(&cur[(p >> 17) & 63], 1);
    sorted[pos] = p;
  }
  __syncthreads();
  // accumulate: 8 threads per node, thread q owns classes 4q..4q+3
  int nl = tid >> 3;
  int q = tid & 7;
  int es = off[nl], ee = off[nl + 1];
  int node = (b4 << 6) + nl;
  if (node >= N_NODES) return;
  const float4* y4 = (const float4*)y;
  const unsigned* yh2 = (const unsigned*)yh;   // row stride 16 uints
  float4 bq = ((const float4*)bias)[q];
  float4 self = y4[(size_t)node * 8 + q];
  float4 acc;
  acc.x = self.x + bq.x;
  acc.y = self.y + bq.y;
  acc.z = self.z + bq.z;
  acc.w = self.w + bq.w;
  int j = es;
  for (; j + 4 <= ee; j += 4) {
    unsigned s0 = sorted[j] & 0x1FFFF, s1 = sorted[j + 1] & 0x1FFFF;
    unsigned s2 = sorted[j + 2] & 0x1FFFF, s3 = sorted[j + 3] & 0x1FFFF;
    uint2 v0 = *(const uint2*)(yh2 + (size_t)s0 * 16 + q * 2);
    uint2 v1 = *(const uint2*)(yh2 + (size_t)s1 * 16 + q * 2);
    uint2 v2 = *(const uint2*)(yh2 + (size_t)s2 * 16 + q * 2);
    uint2 v3 = *(const uint2*)(yh2 + (size_t)s3 * 16 + q * 2);
    acc.x += __uint_as_float(v0.x << 16) + __uint_as_float(v1.x << 16) +
             __uint_as_float(v2.x << 16) + __uint_as_float(v3.x << 16);
    acc.y += __uint_as_float(v0.x & 0xFFFF0000u) + __uint_as_float(v1.x & 0xFFFF0000u) +
             __uint_as_float(v2.x & 0xFFFF0000u) + __uint_as_float(v3.x & 0xFFFF0000u);
    acc.z += __uint_as_float(v0.y << 16) + __uint_as_float(v1.y << 16) +
             __uint_as_float(v2.y << 16) + __uint_as_float(v3.y << 16);
    acc.w += __uint_as_float(v0.y & 0xFFFF0000u) + __uint_as_float(v1.y & 0xFFFF0000u) +
             __uint_as_float(v2.y & 0xFFFF0000u) + __uint_as_float(v3.y & 0xFFFF0000u);
  }
  for (; j < ee; ++j) {
    unsigned s = sorted[j] & 0x1FFFF;
    uint2 v = *(const uint2*)(yh2 + (size_t)s * 16 + q * 2);
    acc.x += __uint_as_float(v.x << 16);
    acc.y += __uint_as_float(v.x & 0xFFFF0000u);
    acc.z += __uint_as_float(v.y << 16);
    acc.w += __uint_as_float(v.y & 0xFFFF0000u);
  }
  ((float4*)out)[(size_t)node * 8 + q] = acc;
}

// ---------- fallback: bias init + atomic scatter (exact, f32 y) ----------
__global__ __launch_bounds__(256) void gin_bias_init(
    const float* __restrict__ y, const float* __restrict__ b,
    float* __restrict__ out) {
  int gid = blockIdx.x * 256 + threadIdx.x;
  if (gid < N_NODES * N_CLASSES) out[gid] = y[gid] + b[gid & 31];
}
__global__ __launch_bounds__(256) void gin_scatter_fb(
    const int* __restrict__ src, const int* __restrict__ dst,
    const float* __restrict__ y, float* __restrict__ out, int n_edges) {
  long long gid = (long long)blockIdx.x * 256 + threadIdx.x;
  int e = (int)(gid >> 5);
  int c = (int)(gid & 31);
  if (e >= n_edges) return;
  atomicAdd(&out[(size_t)dst[e] * N_CLASSES + c],
            y[(size_t)src[e] * N_CLASSES + c]);
}

extern "C" void kernel_launch(void* const* d_in, const int* in_sizes, int n_in,
                              void* d_out, int out_size, void* d_ws, size_t ws_size,
                              hipStream_t stream) {
  const float* x = (const float*)d_in[0];
  const int* edge_index = (const int*)d_in[1];
  const float* W = (const float*)d_in[2];
  const float* b = (const float*)d_in[3];
  float* out = (float*)d_out;

  int E = in_sizes[1] / 2;
  const int* src = edge_index;
  const int* dst = edge_index + E;

  int GBr = (E + EPB - 1) / EPB;      // 98 for E=1.6M
  int pblocks = (N_NODES + 63) / 64;  // 1563 projection blocks

  char* ws = (char*)d_ws;
  size_t sz_y = (size_t)N_NODES * N_CLASSES * 4;                  // 12.8 MB
  size_t sz_yh = (((size_t)N_NODES * N_CLASSES * 2) + 15) & ~15ull; // 6.4 MB
  size_t sz_wb = (D_FEAT * N_CLASSES * 2 + 15) & ~15ull;          // 8 KB bf16 W
  size_t sz_bucketed = (((size_t)NB4 * CAPB4 * 4) + 15) & ~15ull; // 8.0 MB
  size_t sz_gcnt = ((size_t)NB4 * 4 + 15) & ~15ull;

  float* y = (float*)ws;
  unsigned short* yh = (unsigned short*)(ws + sz_y);
  unsigned short* Wb = (unsigned short*)(ws + sz_y + sz_yh);
  unsigned* bucketed = (unsigned*)(ws + sz_y + sz_yh + sz_wb);
  int* gcount = (int*)(ws + sz_y + sz_yh + sz_wb + sz_bucketed);
  size_t need = sz_y + sz_yh + sz_wb + sz_bucketed + sz_gcnt;

  // capacity guard: CAPB4=1280 covers mean E/1563 + 8 sigma up to E ~ 1.8M
  bool dense = E > 1750000;

  if (ws_size < need || dense) {
    gin_prep<<<16, 256, 0, stream>>>(W, Wb, (int*)ws);  // scratch; y overwritten next
    gin_mid<<<pblocks, 256, 0, stream>>>(x, Wb, y, yh, src, dst,
                                         (int*)ws, (unsigned*)ws, E, 0);
    gin_bias_init<<<(N_NODES * N_CLASSES + 255) / 256, 256, 0, stream>>>(y, b, out);
    long long t2 = (long long)E * N_CLASSES;
    gin_scatter_fb<<<(int)((t2 + 255) / 256), 256, 0, stream>>>(src, dst, y, out, E);
    return;
  }

  gin_prep<<<16, 256, 0, stream>>>(W, Wb, gcount);
  gin_mid<<<GBr + pblocks, 256, 0, stream>>>(x, Wb, y, yh, src, dst,
                                             gcount, bucketed, E, GBr);
  gin_gather_s<<<NB4, 512, 0, stream>>>(gcount, bucketed, y, yh, b, out);
}